// Round 5
// baseline (357.127 us; speedup 1.0000x reference)
//
#include <hip/hip_runtime.h>

// Problem constants (fixed by the reference):
#define E_ENV  8192
#define A_AG   128
#define K_PASS 512
#define ROW_F  11
#define SLICE_F  (K_PASS * ROW_F)   // 5632 floats per env slice
#define SLICE_V4 (SLICE_F / 4)      // 1408 float4 per env slice
#define ITERS    (SLICE_V4 / A_AG)  // 11 float4s per thread (1408 = 128*11)

// Overlay encoding (one int per local passenger):
//   bit 9 = pick succeeded, bit 8 = accepted, bits 6..0 = winning agent id
#define OV_PICK 0x200
#define OV_ACC  0x100

// ---------------------------------------------------------------------------
// Single fused kernel, one block (128 threads, 2 waves) per env.
//
// Rounds 1-4 all failed the same way: slice data prefetched into VGPRs must
// stay live across the resolve barriers, and the compiler (legally) sinks
// the __restrict__ loads past __syncthreads into the consume loop no matter
// how they are pinned (VGPR_Count stayed 32 every round) -> 1 load in
// flight/wave -> ~2.3 TB/s latency bind.
//
// Fix: prefetch into LDS via __builtin_amdgcn_global_load_lds. The intrinsic
// WRITES LDS, and __syncthreads is an LDS fence, so it cannot sink past the
// resolve phase -- placement guaranteed, no VGPR liveness involved. 11 async
// 1 KB loads per wave stay in flight under the whole resolve; the final
// __syncthreads (vmcnt(0)+barrier) guarantees arrival; the patch loop then
// reads LDS (~120 cy, TLP-hidden) and streams stores at full BW.
//
// LDS: 22528 (slice) + 2048 (cnt) + 2048 (ov) + 16 = 26640 B -> 6 blocks/CU,
// 12 waves/CU, ~130 KB global in flight per CU >> 22 KB BDP.
//
// Traffic: inline patch, each output line written exactly once (no RMW).
// ---------------------------------------------------------------------------
__global__ __launch_bounds__(128) void k_fused(
    const float4* __restrict__ pass4,
    const int*    __restrict__ accepts,
    const int*    __restrict__ picks,
    const int*    __restrict__ targets,
    const float4* __restrict__ vectors,
    const int*    __restrict__ timesteps,
    float4*       __restrict__ out4)
{
    __shared__ float4 slice[SLICE_V4];   // 22528 B staged env slice
    __shared__ int    cnt[K_PASS];       // dup counter per local passenger
    __shared__ int    ov[K_PASS];        // packed overlay (OV_* bits)
    __shared__ float  swv[2];
    __shared__ int    swi[2];

    const int e   = blockIdx.x;
    const int a   = threadIdx.x;            // agent 0..127
    const int gid = e * A_AG + a;

    // ---- resolve inputs first: they occupy the OLDEST vmcnt slots, so the
    //      compiler's waits for them do not drain the slice staging queue ----
    float4 v = vectors[gid];
    const int  t    = targets[gid];          // global passenger id in [e*K,(e+1)*K)
    const bool acc  = accepts[gid] != 0;
    const bool pick = picks[gid] != 0;
    const float tsf = (float)timesteps[e];

    // ---- async stage: global -> LDS, 16 B/lane, 11 x 1 KB per wave in flight.
    //      Lane-contiguous dest (slice[it*128 + a]) matches the wave-uniform
    //      base + lane*16 hardware rule. ----
    const float4* src = pass4 + (size_t)e * SLICE_V4;
    #pragma unroll
    for (int it = 0; it < ITERS; ++it) {
        const int idx = a + it * A_AG;
        __builtin_amdgcn_global_load_lds(
            (const __attribute__((address_space(1))) void*)(src + idx),
            (__attribute__((address_space(3))) void*)(&slice[idx]),
            16, 0, 0);
    }

    // zero the per-env overlay
    #pragma unroll
    for (int j = 0; j < K_PASS / A_AG; ++j) {
        cnt[a + j * A_AG] = 0;
        ov [a + j * A_AG] = 0;
    }
    __syncthreads();

    // ---- stage ----
    bool invalid = (v.x == -100.0f) && (v.y == -100.0f) &&
                   (v.z == -100.0f) && (v.w == -100.0f);
    float dx = v.x - v.z, dy = v.y - v.w;
    float d = sqrtf(dx * dx + dy * dy);
    if (invalid) d = INFINITY;

    const int tl = t - e * K_PASS;           // local 0..511

    int at = acc ? t : -100;
    if (at >= 0) atomicAdd(&cnt[tl], 1);
    __syncthreads();

    // ---- resolve (single iteration of the reference while_loop: the body
    //       keeps only the env-wide argmin among ALL dup agents, killing
    //       every other dup in one shot -> loop terminates after one pass) ----
    bool dup = (at >= 0) && (cnt[tl] > 1);
    float bv = dup ? d : INFINITY;
    int   bi = a;

    // wave-64 butterfly argmin, first-index tie-break
    #pragma unroll
    for (int off = 32; off > 0; off >>= 1) {
        float ovv = __shfl_xor(bv, off);
        int   oii = __shfl_xor(bi, off);
        if (ovv < bv || (ovv == bv && oii < bi)) { bv = ovv; bi = oii; }
    }
    int wave = a >> 6;
    if ((a & 63) == 0) { swv[wave] = bv; swi[wave] = bi; }
    __syncthreads();
    float v0 = swv[0], v1 = swv[1];
    int   i0 = swi[0], i1 = swi[1];
    // tie -> smaller index (wave 0) wins: matches jnp.argmin first-index
    int bidx = (v1 < v0 || (v1 == v0 && i1 < i0)) ? i1 : i0;

    int f = (dup && a != bidx) ? -100 : at;

    // build packed overlay (atomicOr: accept-winner and pick may be
    // different threads hitting the same passenger)
    if (f >= 0)            atomicOr(&ov[tl], OV_ACC | a);
    if (pick && d < 1e-6f) atomicOr(&ov[tl], OV_PICK);

    // drains vmcnt(0)+lgkmcnt(0) then barrier: slice resident, overlay done
    __syncthreads();

    // ---- streaming store with inline patch ----
    auto patch = [&](float val, unsigned row, int col) -> float {
        int o = ov[row];
        if (col == 6) {
            if (o & OV_PICK) return 2.0f;          // pick overrides accept
            if (o & OV_ACC)  return 1.0f;
        } else if (col == 7) {
            if (o & OV_ACC)  return (float)(o & 0x7f);
        } else if (col == 9) {
            if (o & OV_ACC)  return tsf;
        } else if (col == 10) {
            if (o & OV_PICK) return tsf;
        }
        return val;
    };

    float4* dst = out4 + (size_t)e * SLICE_V4;
    #pragma unroll
    for (int it = 0; it < ITERS; ++it) {
        int idx = a + it * A_AG;                  // float4 index within slice
        float4 y = slice[idx];
        unsigned g   = (unsigned)idx * 4u;        // element index 0..5631
        unsigned row = g / 11u;                   // magic-mul, cheap
        int      col = (int)(g - row * 11u);
        y.x = patch(y.x, row, col); if (++col == 11) { col = 0; ++row; }
        y.y = patch(y.y, row, col); if (++col == 11) { col = 0; ++row; }
        y.z = patch(y.z, row, col); if (++col == 11) { col = 0; ++row; }
        y.w = patch(y.w, row, col);
        dst[idx] = y;
    }
}

// ---------------------------------------------------------------------------
extern "C" void kernel_launch(void* const* d_in, const int* in_sizes, int n_in,
                              void* d_out, int out_size, void* d_ws, size_t ws_size,
                              hipStream_t stream)
{
    const float* passengers = (const float*)d_in[0];
    const int*   accepts    = (const int*)d_in[1];
    const int*   picks      = (const int*)d_in[2];
    const int*   targets    = (const int*)d_in[3];
    const float* vectors    = (const float*)d_in[4];
    const int*   timesteps  = (const int*)d_in[5];
    float*       out        = (float*)d_out;

    k_fused<<<E_ENV, A_AG, 0, stream>>>(
        (const float4*)passengers, accepts, picks, targets,
        (const float4*)vectors, timesteps, (float4*)out);
}

// Round 6
// 330.843 us; speedup vs baseline: 1.0794x; 1.0794x over previous
//
#include <hip/hip_runtime.h>

// Problem constants (fixed by the reference):
#define E_ENV  8192
#define A_AG   128
#define K_PASS 512
#define ROW_F  11
#define SLICE_F  (K_PASS * ROW_F)   // 5632 floats per env slice
#define SLICE_V4 (SLICE_F / 4)      // 1408 float4 per env slice
#define ITERS    (SLICE_V4 / A_AG)  // 11 float4s per thread (1408 = 128*11)

// ---------------------------------------------------------------------------
// Single fused kernel, one block (128 threads, 2 waves) per env.
//
// r5 evidence: __syncthreads() == s_waitcnt vmcnt(0) lgkmcnt(0) + s_barrier.
// Placing it right after the 11 global_load_lds issues drained the staging
// queue BEFORE the resolve ran -> staging serialized, 1.6 TB/s, 181 us.
//
// This version keeps the staging loads in flight across the whole resolve:
//  - intermediate barriers are raw s_barrier + lgkmcnt(0) ONLY (LDS ordering
//    is all they must provide); vmcnt is never drained mid-resolve.
//  - input loads are anchored BEFORE the staging issue via a laundered
//    always-zero value (asm v_and) folded into the staging address: the
//    staging instruction data-depends on the inputs, so the compiler cannot
//    reorder input waits after it (pins failed in r2-r4; dependencies can't).
//  - the one full __syncthreads sits exactly where vmcnt(0) is REQUIRED:
//    before patching the arrived slice in LDS.
//  - patches are applied in LDS (accept phase, barrier, pick-override
//    phase), so the final stream is a pure LDS->global copy.
//
// LDS: 22528 (slice) + 2048 (cnt) + 16 = 24592 B -> 6 blocks/CU, 12 waves.
// Traffic: each output line written exactly once (no RMW); FETCH ~105 MB
// (L3 absorbs part of the passenger reads), WRITE ~180 MB.
// ---------------------------------------------------------------------------

// LDS-only barrier: orders ds ops across the block WITHOUT draining vmcnt,
// so the async global->LDS staging stays in flight across it.
__device__ __forceinline__ void bar_lds()
{
    asm volatile("s_waitcnt lgkmcnt(0)" ::: "memory");
    __builtin_amdgcn_s_barrier();
    asm volatile("" ::: "memory");
}

__global__ __launch_bounds__(128) void k_fused(
    const float4* __restrict__ pass4,
    const int*    __restrict__ accepts,
    const int*    __restrict__ picks,
    const int*    __restrict__ targets,
    const float4* __restrict__ vectors,
    const int*    __restrict__ timesteps,
    float4*       __restrict__ out4)
{
    __shared__ float4 slice4[SLICE_V4];  // 22528 B staged env slice
    __shared__ int    cnt[K_PASS];       // dup counter per local passenger
    __shared__ float  swv[2];
    __shared__ int    swi[2];

    const int e   = blockIdx.x;
    const int a   = threadIdx.x;            // agent 0..127
    const int gid = e * A_AG + a;

    // ---- inputs (must complete before staging issues: see launder below) ----
    float4 v = vectors[gid];
    const int t    = targets[gid];          // global passenger id in [e*K,(e+1)*K)
    const int acc  = accepts[gid];
    const int pick = picks[gid];

    bool invalid = (v.x == -100.0f) && (v.y == -100.0f) &&
                   (v.z == -100.0f) && (v.w == -100.0f);
    float dx = v.x - v.z, dy = v.y - v.w;
    float d = sqrtf(dx * dx + dy * dy);
    if (invalid) d = INFINITY;

    const int tl = t - e * K_PASS;          // local 0..511
    int at = (acc != 0) ? t : -100;

    // Launder an always-zero value through opaque asm so the staging address
    // DATA-DEPENDS on every input load: the compiler must place the input
    // waits before the staging issue, and can never drain the staging queue
    // to satisfy them (they are the OLDEST vmcnt entries).
    int mix = t ^ acc ^ pick ^ __float_as_int(d);
    int z;                                   // == 0, but unknowable
    asm("v_and_b32 %0, 0, %1" : "=v"(z) : "v"(mix));

    // ---- async stage: global -> LDS, 11 x 1 KB per wave in flight.
    //      Lane-contiguous dest matches the wave-uniform base + lane*16 rule. ----
    const float4* src = pass4 + (size_t)e * SLICE_V4 + z;
    #pragma unroll
    for (int it = 0; it < ITERS; ++it) {
        const int idx = a + it * A_AG;
        __builtin_amdgcn_global_load_lds(
            (const __attribute__((address_space(1))) void*)(src + idx),
            (__attribute__((address_space(3))) void*)(&slice4[idx]),
            16, 0, 0);
    }

    // ---- resolve (overlaps the staging flight; LDS-only barriers) ----
    #pragma unroll
    for (int j = 0; j < K_PASS / A_AG; ++j)
        cnt[a + j * A_AG] = 0;
    bar_lds();

    if (at >= 0) atomicAdd(&cnt[tl], 1);
    bar_lds();

    // single iteration of the reference while_loop: the body keeps only the
    // env-wide argmin among ALL dup agents, killing every other dup in one
    // shot -> the loop terminates after one pass.
    bool dup = (at >= 0) && (cnt[tl] > 1);
    float bv = dup ? d : INFINITY;
    int   bi = a;

    #pragma unroll
    for (int off = 32; off > 0; off >>= 1) {   // wave-64 butterfly argmin
        float ov = __shfl_xor(bv, off);
        int   oi = __shfl_xor(bi, off);
        if (ov < bv || (ov == bv && oi < bi)) { bv = ov; bi = oi; }
    }
    int wave = a >> 6;
    if ((a & 63) == 0) { swv[wave] = bv; swi[wave] = bi; }
    bar_lds();
    float v0 = swv[0], v1 = swv[1];
    int   i0 = swi[0], i1 = swi[1];
    // tie -> smaller index (wave 0) wins: matches jnp.argmin first-index
    int bidx = (v1 < v0 || (v1 == v0 && i1 < i0)) ? i1 : i0;

    int f = (dup && a != bidx) ? -100 : at;

    // ---- the ONE full barrier: staging arrival (vmcnt(0)) is required
    //      before patching rows in the staged slice ----
    __syncthreads();

    float* sliceF = (float*)slice4;
    const float tsf = (float)timesteps[e];

    // accept patch: at most one surviving agent per passenger -> no race
    if (f >= 0) {
        sliceF[tl * ROW_F + 6] = 1.0f;
        sliceF[tl * ROW_F + 7] = (float)a;
        sliceF[tl * ROW_F + 9] = tsf;
    }
    bar_lds();
    // pick override (reference order: col6=2.0 overwrites accept's 1.0;
    // multi-writers store identical values -> benign)
    if ((pick != 0) && d < 1e-6f) {
        sliceF[tl * ROW_F + 6]  = 2.0f;
        sliceF[tl * ROW_F + 10] = tsf;
    }
    bar_lds();

    // ---- pure streaming copy LDS -> global (no per-element logic) ----
    float4* dst = out4 + (size_t)e * SLICE_V4;
    #pragma unroll
    for (int it = 0; it < ITERS; ++it) {
        const int idx = a + it * A_AG;
        dst[idx] = slice4[idx];
    }
}

// ---------------------------------------------------------------------------
extern "C" void kernel_launch(void* const* d_in, const int* in_sizes, int n_in,
                              void* d_out, int out_size, void* d_ws, size_t ws_size,
                              hipStream_t stream)
{
    const float* passengers = (const float*)d_in[0];
    const int*   accepts    = (const int*)d_in[1];
    const int*   picks      = (const int*)d_in[2];
    const int*   targets    = (const int*)d_in[3];
    const float* vectors    = (const float*)d_in[4];
    const int*   timesteps  = (const int*)d_in[5];
    float*       out        = (float*)d_out;

    k_fused<<<E_ENV, A_AG, 0, stream>>>(
        (const float4*)passengers, accepts, picks, targets,
        (const float4*)vectors, timesteps, (float4*)out);
}